// Round 2
// baseline (1164.017 us; speedup 1.0000x reference)
//
#include <hip/hip_runtime.h>
#include <hip/hip_bf16.h>
#include <stdint.h>

#define NN 50000
#define EE 800000
#define DD 256
#define LL 3

using floatx4 = __attribute__((ext_vector_type(4))) float;
using shortx8 = __attribute__((ext_vector_type(8))) short;

union U8 { shortx8 v; uint32_t u[4]; };

__device__ __forceinline__ uint16_t f2bf(float f) {
    __hip_bfloat16 h = __float2bfloat16(f);
    return *reinterpret_cast<uint16_t*>(&h);
}
// split fp32 pair -> packed bf16 hi (truncated) + packed bf16 lo (RNE of remainder)
__device__ __forceinline__ uint32_t packsplit(float f0, float f1, uint32_t& lo) {
    uint32_t u0 = __float_as_uint(f0), u1 = __float_as_uint(f1);
    float l0 = f0 - __uint_as_float(u0 & 0xFFFF0000u);
    float l1 = f1 - __uint_as_float(u1 & 0xFFFF0000u);
    lo = (uint32_t)f2bf(l0) | ((uint32_t)f2bf(l1) << 16);
    return (u0 >> 16) | (u1 & 0xFFFF0000u);
}

// ---------------- CSR build ----------------
__global__ void k_count(const int* __restrict__ tgt, int* __restrict__ deg) {
    int e = blockIdx.x * 256 + threadIdx.x;
    if (e < EE) atomicAdd(&deg[tgt[e]], 1);
}

__global__ void k_scan(const int* __restrict__ deg, int* __restrict__ row_start) {
    __shared__ int wsum[16];
    __shared__ int carry;
    int t = threadIdx.x;            // 1024
    int w = t >> 6, lane = t & 63;
    if (t == 0) carry = 0;
    __syncthreads();
    for (int base = 0; base < NN; base += 1024) {
        int i = base + t;
        int v = (i < NN) ? deg[i] : 0;
        int s = v;
#pragma unroll
        for (int off = 1; off < 64; off <<= 1) {
            int u = __shfl_up(s, off);
            if (lane >= off) s += u;
        }
        if (lane == 63) wsum[w] = s;
        __syncthreads();
        if (w == 0 && lane < 16) {
            int ws = wsum[lane];
#pragma unroll
            for (int off = 1; off < 16; off <<= 1) {
                int u = __shfl_up(ws, off);
                if (lane >= off) ws += u;
            }
            wsum[lane] = ws;
        }
        __syncthreads();
        int wprefix = (w > 0) ? wsum[w - 1] : 0;
        int incl = carry + wprefix + s;
        if (i < NN) row_start[i] = incl - v;   // exclusive
        __syncthreads();
        if (t == 1023) carry = incl;
        __syncthreads();
    }
    if (t == 0) row_start[NN] = carry;
}

__global__ void k_init(const int* __restrict__ deg, const int* __restrict__ row_start,
                       int* __restrict__ cursor, float* __restrict__ invd) {
    int i = blockIdx.x * 256 + threadIdx.x;
    if (i < NN) {
        cursor[i] = row_start[i];
        int d = deg[i];
        invd[i] = d > 0 ? 1.0f / (float)d : 0.0f;
    }
}

__global__ void k_scatter(const int* __restrict__ src, const int* __restrict__ tgt,
                          int* __restrict__ cursor, int* __restrict__ csr) {
    int e = blockIdx.x * 256 + threadIdx.x;
    if (e < EE) {
        int p = atomicAdd(&cursor[tgt[e]], 1);
        csr[p] = src[e];
    }
}

// ------- weight prep: fp32 W[i][k][n] -> transposed bf16 hi/lo Wt[i][n][k] -------
__global__ void k_wprep(const float* __restrict__ Wl, const float* __restrict__ Wr,
                        uint16_t* __restrict__ wtl_hi, uint16_t* __restrict__ wtl_lo,
                        uint16_t* __restrict__ wtr_hi, uint16_t* __restrict__ wtr_lo) {
    int d = blockIdx.x * 256 + threadIdx.x;   // dest flat index, k fastest
    int i = d >> 16, n = (d >> 8) & 255, k = d & 255;
    int s = (i << 16) | (k << 8) | n;
    float wl = Wl[s], wr = Wr[s];
    uint32_t ul = __float_as_uint(wl), ur = __float_as_uint(wr);
    wtl_hi[d] = (uint16_t)(ul >> 16);
    wtl_lo[d] = f2bf(wl - __uint_as_float(ul & 0xFFFF0000u));
    wtr_hi[d] = (uint16_t)(ur >> 16);
    wtr_lo[d] = f2bf(wr - __uint_as_float(ur & 0xFFFF0000u));
}

// ---------------- mean aggregation: one wave per node, fp32 ----------------
__global__ void k_aggregate(const int* __restrict__ row_start, const int* __restrict__ csr,
                            const float* __restrict__ invd, const float* __restrict__ x,
                            int xstride, float* __restrict__ agg) {
    int node = blockIdx.x * 4 + (threadIdx.x >> 6);
    if (node >= NN) return;
    int lane = threadIdx.x & 63;
    int col = lane * 4;                  // 64 lanes x 16B = full 1KB row
    int s = row_start[node], e = row_start[node + 1];
    float a0 = 0.f, a1 = 0.f, a2 = 0.f, a3 = 0.f;
    for (int s0 = s; s0 < e; s0 += 64) {
        int cnt = min(64, e - s0);
        int my = (lane < cnt) ? csr[s0 + lane] : 0;
        for (int j = 0; j < cnt; ++j) {
            int sidx = __shfl(my, j);
            float4 v = *reinterpret_cast<const float4*>(x + (size_t)sidx * xstride + col);
            a0 += v.x; a1 += v.y; a2 += v.z; a3 += v.w;
        }
    }
    float wgt = invd[node];
    float4 r; r.x = a0 * wgt; r.y = a1 * wgt; r.z = a2 * wgt; r.w = a3 * wgt;
    *reinterpret_cast<float4*>(agg + (size_t)node * DD + col) = r;
}

// ---- fused split-bf16 GEMM: out = relu?(agg@Wl + x@Wr + b + x), fp32 in/out ----
// Block: 4 waves over 64 rows x 256 cols. Wave = 32 rows (2 MFMA row-tiles) x
// 128 cols (8 col-tiles). A split in-register fp32->bf16 hi/lo; 3 MFMA per
// product pair (hh, hl, lh); lo*lo dropped (2^-16 rel).
__global__ __launch_bounds__(256) void k_gemm(
    const float* __restrict__ agg,
    const float* __restrict__ xin, int xstride,
    const uint16_t* __restrict__ wlh, const uint16_t* __restrict__ wll,
    const uint16_t* __restrict__ wrh, const uint16_t* __restrict__ wrl,
    const float* __restrict__ bias,
    float* __restrict__ outp,
    int do_relu)
{
    int wave = threadIdx.x >> 6;
    int lane = threadIdx.x & 63;
    int quad = lane >> 4;
    int l16  = lane & 15;
    int m0    = blockIdx.x * 64 + (wave & 1) * 32;   // wave's 32-row start
    int nbase = (wave >> 1) * 128;                   // wave's 128-col half

    floatx4 acc[2][8];
#pragma unroll
    for (int rt = 0; rt < 2; ++rt)
#pragma unroll
        for (int ct = 0; ct < 8; ++ct)
            acc[rt][ct] = (floatx4){0.f, 0.f, 0.f, 0.f};

    int row0 = m0 + l16;          // rt=0 A row
    int row1 = m0 + 16 + l16;     // rt=1 A row
    int r0c = row0 < NN ? row0 : NN - 1;
    int r1c = row1 < NN ? row1 : NN - 1;

    for (int k0 = 0; k0 < 256; k0 += 32) {
        int kf = k0 + quad * 8;
        U8 ahi[2][2], alo[2][2];   // [rowtile][term: 0=agg, 1=x]
#pragma unroll
        for (int rt = 0; rt < 2; ++rt) {
            int rc = rt ? r1c : r0c;
            const float* ap = agg + (size_t)rc * DD + kf;
            float4 p0 = *reinterpret_cast<const float4*>(ap);
            float4 p1 = *reinterpret_cast<const float4*>(ap + 4);
            ahi[rt][0].u[0] = packsplit(p0.x, p0.y, alo[rt][0].u[0]);
            ahi[rt][0].u[1] = packsplit(p0.z, p0.w, alo[rt][0].u[1]);
            ahi[rt][0].u[2] = packsplit(p1.x, p1.y, alo[rt][0].u[2]);
            ahi[rt][0].u[3] = packsplit(p1.z, p1.w, alo[rt][0].u[3]);
            const float* xp = xin + (size_t)rc * xstride + kf;
            float4 q0 = *reinterpret_cast<const float4*>(xp);
            float4 q1 = *reinterpret_cast<const float4*>(xp + 4);
            ahi[rt][1].u[0] = packsplit(q0.x, q0.y, alo[rt][1].u[0]);
            ahi[rt][1].u[1] = packsplit(q0.z, q0.w, alo[rt][1].u[1]);
            ahi[rt][1].u[2] = packsplit(q1.x, q1.y, alo[rt][1].u[2]);
            ahi[rt][1].u[3] = packsplit(q1.z, q1.w, alo[rt][1].u[3]);
        }
#pragma unroll
        for (int ct = 0; ct < 8; ++ct) {
            size_t boff = ((size_t)(nbase + ct * 16 + l16) << 8) + kf;
            shortx8 blh = *reinterpret_cast<const shortx8*>(wlh + boff);
            shortx8 bll = *reinterpret_cast<const shortx8*>(wll + boff);
            shortx8 brh = *reinterpret_cast<const shortx8*>(wrh + boff);
            shortx8 brl = *reinterpret_cast<const shortx8*>(wrl + boff);
#pragma unroll
            for (int rt = 0; rt < 2; ++rt) {
                acc[rt][ct] = __builtin_amdgcn_mfma_f32_16x16x32_bf16(ahi[rt][0].v, blh, acc[rt][ct], 0, 0, 0);
                acc[rt][ct] = __builtin_amdgcn_mfma_f32_16x16x32_bf16(ahi[rt][0].v, bll, acc[rt][ct], 0, 0, 0);
                acc[rt][ct] = __builtin_amdgcn_mfma_f32_16x16x32_bf16(alo[rt][0].v, blh, acc[rt][ct], 0, 0, 0);
                acc[rt][ct] = __builtin_amdgcn_mfma_f32_16x16x32_bf16(ahi[rt][1].v, brh, acc[rt][ct], 0, 0, 0);
                acc[rt][ct] = __builtin_amdgcn_mfma_f32_16x16x32_bf16(ahi[rt][1].v, brl, acc[rt][ct], 0, 0, 0);
                acc[rt][ct] = __builtin_amdgcn_mfma_f32_16x16x32_bf16(alo[rt][1].v, brh, acc[rt][ct], 0, 0, 0);
            }
        }
    }

    // Epilogue: D[row=quad*4+r][col=l16] per tile; +bias +residual (+relu), fp32 out.
#pragma unroll
    for (int rt = 0; rt < 2; ++rt)
#pragma unroll
        for (int ct = 0; ct < 8; ++ct)
#pragma unroll
            for (int r = 0; r < 4; ++r) {
                int row = m0 + rt * 16 + quad * 4 + r;
                if (row < NN) {
                    int col = nbase + ct * 16 + l16;
                    float v = acc[rt][ct][r] + bias[col] + xin[(size_t)row * xstride + col];
                    if (do_relu) v = fmaxf(v, 0.f);
                    outp[(size_t)row * (LL * DD) + col] = v;
                }
            }
}

extern "C" void kernel_launch(void* const* d_in, const int* in_sizes, int n_in,
                              void* d_out, int out_size, void* d_ws, size_t ws_size,
                              hipStream_t stream) {
    const int*   edge   = (const int*)d_in[0];     // [2][E]: row0=src, row1=tgt
    const float* x_init = (const float*)d_in[1];   // [N][D] fp32
    const float* W_l    = (const float*)d_in[2];   // [L][D][D] fp32
    const float* W_r    = (const float*)d_in[3];   // [L][D][D] fp32
    const float* bias   = (const float*)d_in[4];   // [L][D] fp32
    float*       out    = (float*)d_out;           // [N][L*D] fp32

    char* ws = (char*)d_ws;
    int*      degI      = (int*)(ws);
    int*      row_start = (int*)(ws + 256 * 1024);
    int*      cursor    = (int*)(ws + 512 * 1024);
    float*    invd      = (float*)(ws + 768 * 1024);
    int*      csr       = (int*)(ws + 1048576);          // 3.2 MB
    uint16_t* wtl_hi    = (uint16_t*)(ws + 4456448);     // 384 KB each
    uint16_t* wtl_lo    = (uint16_t*)(ws + 4980736);
    uint16_t* wtr_hi    = (uint16_t*)(ws + 5505024);
    uint16_t* wtr_lo    = (uint16_t*)(ws + 6029312);
    float*    agg       = (float*)(ws + 6553600);        // 51.2 MB

    hipMemsetAsync(degI, 0, NN * sizeof(int), stream);
    k_count<<<(EE + 255) / 256, 256, 0, stream>>>(edge + EE, degI);
    k_scan<<<1, 1024, 0, stream>>>(degI, row_start);
    k_init<<<(NN + 255) / 256, 256, 0, stream>>>(degI, row_start, cursor, invd);
    k_scatter<<<(EE + 255) / 256, 256, 0, stream>>>(edge, edge + EE, cursor, csr);
    k_wprep<<<(LL * DD * DD) / 256, 256, 0, stream>>>(W_l, W_r, wtl_hi, wtl_lo, wtr_hi, wtr_lo);

    for (int i = 0; i < LL; ++i) {
        const float* x = (i == 0) ? x_init : (out + (size_t)(i - 1) * DD);
        int xs = (i == 0) ? DD : LL * DD;
        size_t wo = (size_t)i * DD * DD;
        k_aggregate<<<(NN + 3) / 4, 256, 0, stream>>>(row_start, csr, invd, x, xs, agg);
        k_gemm<<<(NN + 63) / 64, 256, 0, stream>>>(
            agg, x, xs,
            wtl_hi + wo, wtl_lo + wo, wtr_hi + wo, wtr_lo + wo,
            bias + (size_t)i * DD,
            out + (size_t)i * DD,
            (i < LL - 1) ? 1 : 0);
    }
}

// Round 3
// 1103.924 us; speedup vs baseline: 1.0544x; 1.0544x over previous
//
#include <hip/hip_runtime.h>
#include <hip/hip_bf16.h>
#include <stdint.h>

#define NN 50000
#define EE 800000
#define DD 256
#define LL 3
#define NBLK 49   // ceil(NN/1024)

using floatx4 = __attribute__((ext_vector_type(4))) float;
using shortx8 = __attribute__((ext_vector_type(8))) short;

union U8 { shortx8 v; uint32_t u[4]; };

typedef __attribute__((address_space(1))) const unsigned int gu32;
typedef __attribute__((address_space(3))) unsigned int lu32;
__device__ __forceinline__ void async_copy16(const void* g, void* l) {
    __builtin_amdgcn_global_load_lds((gu32*)g, (lu32*)l, 16, 0, 0);
}

__device__ __forceinline__ uint16_t f2bf(float f) {
    __hip_bfloat16 h = __float2bfloat16(f);
    return *reinterpret_cast<uint16_t*>(&h);
}
// split fp32 pair -> packed bf16 hi (truncated) + packed bf16 lo (RNE of remainder)
__device__ __forceinline__ uint32_t packsplit(float f0, float f1, uint32_t& lo) {
    uint32_t u0 = __float_as_uint(f0), u1 = __float_as_uint(f1);
    float l0 = f0 - __uint_as_float(u0 & 0xFFFF0000u);
    float l1 = f1 - __uint_as_float(u1 & 0xFFFF0000u);
    lo = (uint32_t)f2bf(l0) | ((uint32_t)f2bf(l1) << 16);
    return (u0 >> 16) | (u1 & 0xFFFF0000u);
}

// ---------------- CSR build ----------------
__global__ void k_count(const int* __restrict__ tgt, int* __restrict__ deg) {
    int e = blockIdx.x * 256 + threadIdx.x;
    if (e < EE) atomicAdd(&deg[tgt[e]], 1);
}

// per-1024-block exclusive scan + block sums
__global__ void k_scan1(const int* __restrict__ deg, int* __restrict__ row_start,
                        int* __restrict__ bsum) {
    __shared__ int wsum[16];
    int t = threadIdx.x, w = t >> 6, lane = t & 63;
    int i = blockIdx.x * 1024 + t;
    int v = (i < NN) ? deg[i] : 0;
    int s = v;
#pragma unroll
    for (int off = 1; off < 64; off <<= 1) {
        int u = __shfl_up(s, off);
        if (lane >= off) s += u;
    }
    if (lane == 63) wsum[w] = s;
    __syncthreads();
    if (t < 16) {
        int ws = wsum[t];
#pragma unroll
        for (int off = 1; off < 16; off <<= 1) {
            int u = __shfl_up(ws, off);
            if (t >= off) ws += u;
        }
        wsum[t] = ws;
    }
    __syncthreads();
    int off = (w > 0) ? wsum[w - 1] : 0;
    if (i < NN) row_start[i] = off + s - v;          // block-local exclusive
    if (t == 1023) bsum[blockIdx.x] = off + s;       // block total
}

// scan the 49 block sums in-place (exclusive)
__global__ void k_scan2(int* __restrict__ bsum, int* __restrict__ row_start) {
    int t = threadIdx.x;   // 64
    int v = (t < NBLK) ? bsum[t] : 0;
    int s = v;
#pragma unroll
    for (int off = 1; off < 64; off <<= 1) {
        int u = __shfl_up(s, off);
        if (t >= off) s += u;
    }
    if (t < NBLK) bsum[t] = s - v;
    if (t == 0) row_start[NN] = EE;
}

// add block offsets; init cursor + inv-degree
__global__ void k_init2(const int* __restrict__ deg, const int* __restrict__ bsum,
                        int* __restrict__ row_start, int* __restrict__ cursor,
                        float* __restrict__ invd) {
    int i = blockIdx.x * 1024 + threadIdx.x;
    if (i < NN) {
        int r = row_start[i] + bsum[blockIdx.x];
        row_start[i] = r;
        cursor[i] = r;
        int d = deg[i];
        invd[i] = d > 0 ? 1.0f / (float)d : 0.0f;
    }
}

__global__ void k_scatter(const int* __restrict__ src, const int* __restrict__ tgt,
                          int* __restrict__ cursor, int* __restrict__ csr) {
    int e = blockIdx.x * 256 + threadIdx.x;
    if (e < EE) {
        int p = atomicAdd(&cursor[tgt[e]], 1);
        csr[p] = src[e];
    }
}

// ------- weight prep: fp32 W[i][k][n] -> transposed bf16 hi/lo Wt[i][n][k] -------
__global__ void k_wprep(const float* __restrict__ Wl, const float* __restrict__ Wr,
                        uint16_t* __restrict__ wtl_hi, uint16_t* __restrict__ wtl_lo,
                        uint16_t* __restrict__ wtr_hi, uint16_t* __restrict__ wtr_lo) {
    int d = blockIdx.x * 256 + threadIdx.x;   // dest flat index, k fastest
    int i = d >> 16, n = (d >> 8) & 255, k = d & 255;
    int s = (i << 16) | (k << 8) | n;
    float wl = Wl[s], wr = Wr[s];
    uint32_t ul = __float_as_uint(wl), ur = __float_as_uint(wr);
    wtl_hi[d] = (uint16_t)(ul >> 16);
    wtl_lo[d] = f2bf(wl - __uint_as_float(ul & 0xFFFF0000u));
    wtr_hi[d] = (uint16_t)(ur >> 16);
    wtr_lo[d] = f2bf(wr - __uint_as_float(ur & 0xFFFF0000u));
}

// ---- split-bf16 dual GEMM: yl = x@Wl (fp32 out), z = x@Wr + b + x -> out slice ----
// Block: 4 waves, tile 64 rows x 256 cols. Wave: 32 rows (2 rt) x 128 cols (8 ct).
// Weights staged per 32-k chunk in LDS via global_load_lds (hi 16KB + lo 16KB),
// read back as ds_read_b128 fragments. A split in-register (3 MFMA: hh+hl+lh).
__global__ __launch_bounds__(256) void k_gemm2(
    const float* __restrict__ x, int xs,
    const uint16_t* __restrict__ wlh, const uint16_t* __restrict__ wll,
    const uint16_t* __restrict__ wrh, const uint16_t* __restrict__ wrl,
    const float* __restrict__ bias,
    float* __restrict__ yl,          // [N][256] fp32
    float* __restrict__ outz)        // out + layer*256, stride LL*DD
{
    __shared__ __align__(16) uint16_t sw[16384];   // hi [0,16KB) + lo [16KB,32KB)
    int t = threadIdx.x;
    int wave = t >> 6, lane = t & 63, quad = lane >> 4, l16 = lane & 15;
    int m0 = blockIdx.x * 64 + (wave & 1) * 32;
    int nbase = (wave >> 1) * 128;
    int r0 = m0 + l16, r1 = r0 + 16;
    size_t r0c = (size_t)(r0 < NN ? r0 : NN - 1) * xs;
    size_t r1c = (size_t)(r1 < NN ? r1 : NN - 1) * xs;

    // staging source/dest offsets (thread-fixed parts)
    int srcbase = (t >> 2) * 256 + (t & 3) * 8;    // + c*32 + i*64*256
    char* dst0 = (char*)sw + t * 16;               // + i*4096 (hi), +16384 (lo)

    for (int ph = 0; ph < 2; ++ph) {
        const uint16_t* wh = ph ? wrh : wlh;
        const uint16_t* wo = ph ? wrl : wll;
        floatx4 acc[2][8];
#pragma unroll
        for (int rt = 0; rt < 2; ++rt)
#pragma unroll
            for (int ct = 0; ct < 8; ++ct)
                acc[rt][ct] = (floatx4){0.f, 0.f, 0.f, 0.f};

        for (int c = 0; c < 8; ++c) {
            // async-stage this k-chunk of both weight halves into LDS
            {
                const uint16_t* s0 = wh + srcbase + c * 32;
                const uint16_t* s1 = wo + srcbase + c * 32;
#pragma unroll
                for (int i = 0; i < 4; ++i) {
                    async_copy16(s0 + i * 16384, dst0 + i * 4096);
                    async_copy16(s1 + i * 16384, dst0 + 16384 + i * 4096);
                }
            }
            // A fragments: load fp32, split in-register
            int ka = c * 32 + quad * 8;
            const float* a0p = x + r0c + ka;
            const float* a1p = x + r1c + ka;
            float4 p0 = *reinterpret_cast<const float4*>(a0p);
            float4 p1 = *reinterpret_cast<const float4*>(a0p + 4);
            float4 q0 = *reinterpret_cast<const float4*>(a1p);
            float4 q1 = *reinterpret_cast<const float4*>(a1p + 4);
            U8 a0h, a0l, a1h, a1l;
            a0h.u[0] = packsplit(p0.x, p0.y, a0l.u[0]);
            a0h.u[1] = packsplit(p0.z, p0.w, a0l.u[1]);
            a0h.u[2] = packsplit(p1.x, p1.y, a0l.u[2]);
            a0h.u[3] = packsplit(p1.z, p1.w, a0l.u[3]);
            a1h.u[0] = packsplit(q0.x, q0.y, a1l.u[0]);
            a1h.u[1] = packsplit(q0.z, q0.w, a1l.u[1]);
            a1h.u[2] = packsplit(q1.x, q1.y, a1l.u[2]);
            a1h.u[3] = packsplit(q1.z, q1.w, a1l.u[3]);

            __syncthreads();   // drains global_load_lds (vmcnt) -> LDS ready
#pragma unroll
            for (int ct = 0; ct < 8; ++ct) {
                const uint16_t* bp = sw + (nbase + ct * 16 + l16) * 32 + quad * 8;
                shortx8 bh = *reinterpret_cast<const shortx8*>(bp);
                shortx8 bl = *reinterpret_cast<const shortx8*>(bp + 8192);
                acc[0][ct] = __builtin_amdgcn_mfma_f32_16x16x32_bf16(a0h.v, bh, acc[0][ct], 0, 0, 0);
                acc[0][ct] = __builtin_amdgcn_mfma_f32_16x16x32_bf16(a0h.v, bl, acc[0][ct], 0, 0, 0);
                acc[0][ct] = __builtin_amdgcn_mfma_f32_16x16x32_bf16(a0l.v, bh, acc[0][ct], 0, 0, 0);
                acc[1][ct] = __builtin_amdgcn_mfma_f32_16x16x32_bf16(a1h.v, bh, acc[1][ct], 0, 0, 0);
                acc[1][ct] = __builtin_amdgcn_mfma_f32_16x16x32_bf16(a1h.v, bl, acc[1][ct], 0, 0, 0);
                acc[1][ct] = __builtin_amdgcn_mfma_f32_16x16x32_bf16(a1l.v, bh, acc[1][ct], 0, 0, 0);
            }
            __syncthreads();   // before next chunk overwrites LDS
        }

        // epilogue: C/D layout col=l16, row=quad*4+reg
        if (ph == 0) {
#pragma unroll
            for (int rt = 0; rt < 2; ++rt)
#pragma unroll
                for (int ct = 0; ct < 8; ++ct)
#pragma unroll
                    for (int r = 0; r < 4; ++r) {
                        int row = m0 + rt * 16 + quad * 4 + r;
                        if (row < NN)
                            yl[(size_t)row * DD + nbase + ct * 16 + l16] = acc[rt][ct][r];
                    }
        } else {
#pragma unroll
            for (int rt = 0; rt < 2; ++rt)
#pragma unroll
                for (int ct = 0; ct < 8; ++ct)
#pragma unroll
                    for (int r = 0; r < 4; ++r) {
                        int row = m0 + rt * 16 + quad * 4 + r;
                        if (row < NN) {
                            int col = nbase + ct * 16 + l16;
                            float v = acc[rt][ct][r] + bias[col] + x[(size_t)row * xs + col];
                            outz[(size_t)row * (LL * DD) + col] = v;
                        }
                    }
        }
    }
}

// ---- finish: out = maybe_relu(z + invd * sum_nbr yl[src]); one wave per node ----
__global__ __launch_bounds__(256) void k_finish(
    const int* __restrict__ rs, const int* __restrict__ csr,
    const float* __restrict__ invd, const float* __restrict__ yl,
    float* __restrict__ outz, int do_relu)
{
    int node = blockIdx.x * 4 + (threadIdx.x >> 6);
    int lane = threadIdx.x & 63;
    int col = lane * 4;
    int s = rs[node], e = rs[node + 1];
    float a0 = 0.f, a1 = 0.f, a2 = 0.f, a3 = 0.f;
    int p = s;
    for (; p + 4 <= e; p += 4) {
        int i0 = csr[p], i1 = csr[p + 1], i2 = csr[p + 2], i3 = csr[p + 3];
        float4 v0 = *reinterpret_cast<const float4*>(yl + (size_t)i0 * DD + col);
        float4 v1 = *reinterpret_cast<const float4*>(yl + (size_t)i1 * DD + col);
        float4 v2 = *reinterpret_cast<const float4*>(yl + (size_t)i2 * DD + col);
        float4 v3 = *reinterpret_cast<const float4*>(yl + (size_t)i3 * DD + col);
        a0 += (v0.x + v1.x) + (v2.x + v3.x);
        a1 += (v0.y + v1.y) + (v2.y + v3.y);
        a2 += (v0.z + v1.z) + (v2.z + v3.z);
        a3 += (v0.w + v1.w) + (v2.w + v3.w);
    }
    for (; p < e; ++p) {
        int i = csr[p];
        float4 v = *reinterpret_cast<const float4*>(yl + (size_t)i * DD + col);
        a0 += v.x; a1 += v.y; a2 += v.z; a3 += v.w;
    }
    float w = invd[node];
    float* zp = outz + (size_t)node * (LL * DD) + col;
    float4 z = *reinterpret_cast<const float4*>(zp);
    float o0 = z.x + a0 * w, o1 = z.y + a1 * w, o2 = z.z + a2 * w, o3 = z.w + a3 * w;
    if (do_relu) {
        o0 = fmaxf(o0, 0.f); o1 = fmaxf(o1, 0.f);
        o2 = fmaxf(o2, 0.f); o3 = fmaxf(o3, 0.f);
    }
    *reinterpret_cast<float4*>(zp) = make_float4(o0, o1, o2, o3);
}

extern "C" void kernel_launch(void* const* d_in, const int* in_sizes, int n_in,
                              void* d_out, int out_size, void* d_ws, size_t ws_size,
                              hipStream_t stream) {
    const int*   edge   = (const int*)d_in[0];     // [2][E]: row0=src, row1=tgt
    const float* x_init = (const float*)d_in[1];   // [N][D] fp32
    const float* W_l    = (const float*)d_in[2];   // [L][D][D] fp32
    const float* W_r    = (const float*)d_in[3];   // [L][D][D] fp32
    const float* bias   = (const float*)d_in[4];   // [L][D] fp32
    float*       out    = (float*)d_out;           // [N][L*D] fp32

    char* ws = (char*)d_ws;
    int*      degI      = (int*)(ws + 0x000000);     // 200 KB
    int*      row_start = (int*)(ws + 0x040000);     // 200 KB + 4
    int*      cursor    = (int*)(ws + 0x080000);
    float*    invd      = (float*)(ws + 0x0C0000);
    int*      bsum      = (int*)(ws + 0x100000);     // 196 B
    int*      csr       = (int*)(ws + 0x140000);     // 3.2 MB
    uint16_t* wtl_hi    = (uint16_t*)(ws + 0x480000);  // 384 KB each
    uint16_t* wtl_lo    = (uint16_t*)(ws + 0x4E0000);
    uint16_t* wtr_hi    = (uint16_t*)(ws + 0x540000);
    uint16_t* wtr_lo    = (uint16_t*)(ws + 0x5A0000);
    float*    yl        = (float*)(ws + 0x600000);     // 51.2 MB (ends ~57.2 MB)

    hipMemsetAsync(degI, 0, NN * sizeof(int), stream);
    k_count<<<(EE + 255) / 256, 256, 0, stream>>>(edge + EE, degI);
    k_scan1<<<NBLK, 1024, 0, stream>>>(degI, row_start, bsum);
    k_scan2<<<1, 64, 0, stream>>>(bsum, row_start);
    k_init2<<<NBLK, 1024, 0, stream>>>(degI, bsum, row_start, cursor, invd);
    k_scatter<<<(EE + 255) / 256, 256, 0, stream>>>(edge, edge + EE, cursor, csr);
    k_wprep<<<(LL * DD * DD) / 256, 256, 0, stream>>>(W_l, W_r, wtl_hi, wtl_lo, wtr_hi, wtr_lo);

    for (int i = 0; i < LL; ++i) {
        const float* x = (i == 0) ? x_init : (out + (size_t)(i - 1) * DD);
        int xs = (i == 0) ? DD : LL * DD;
        size_t wo = (size_t)i * DD * DD;
        k_gemm2<<<(NN + 63) / 64, 256, 0, stream>>>(
            x, xs,
            wtl_hi + wo, wtl_lo + wo, wtr_hi + wo, wtr_lo + wo,
            bias + (size_t)i * DD,
            yl, out + (size_t)i * DD);
        k_finish<<<NN / 4, 256, 0, stream>>>(
            row_start, csr, invd, yl, out + (size_t)i * DD, (i < LL - 1) ? 1 : 0);
    }
}

// Round 4
// 747.613 us; speedup vs baseline: 1.5570x; 1.4766x over previous
//
#include <hip/hip_runtime.h>
#include <hip/hip_bf16.h>
#include <stdint.h>

#define NN 50000
#define EE 800000
#define DD 256
#define LL 3
#define NBLK 49      // ceil(NN/1024)
#define NPAD 50176   // 196*256

using floatx4 = __attribute__((ext_vector_type(4))) float;
using shortx8 = __attribute__((ext_vector_type(8))) short;

union U8 { shortx8 v; uint32_t u[4]; };

typedef __attribute__((address_space(1))) const unsigned int gu32;
typedef __attribute__((address_space(3))) unsigned int lu32;
__device__ __forceinline__ void async_copy16(const void* g, void* l) {
    __builtin_amdgcn_global_load_lds((gu32*)g, (lu32*)l, 16, 0, 0);
}

__device__ __forceinline__ uint16_t f2bf(float f) {
    __hip_bfloat16 h = __float2bfloat16(f);
    return *reinterpret_cast<uint16_t*>(&h);
}
__device__ __forceinline__ float bf2f(uint32_t u) {
    union { uint32_t u32; float f; } cv; cv.u32 = (u & 0xffffu) << 16; return cv.f;
}

// ---------------- CSR build ----------------
__global__ void k_count(const int* __restrict__ tgt, int* __restrict__ deg) {
    int e = blockIdx.x * 256 + threadIdx.x;
    if (e < EE) atomicAdd(&deg[tgt[e]], 1);
}

__global__ void k_scan1(const int* __restrict__ deg, int* __restrict__ row_start,
                        int* __restrict__ bsum) {
    __shared__ int wsum[16];
    int t = threadIdx.x, w = t >> 6, lane = t & 63;
    int i = blockIdx.x * 1024 + t;
    int v = (i < NN) ? deg[i] : 0;
    int s = v;
#pragma unroll
    for (int off = 1; off < 64; off <<= 1) {
        int u = __shfl_up(s, off);
        if (lane >= off) s += u;
    }
    if (lane == 63) wsum[w] = s;
    __syncthreads();
    if (t < 16) {
        int ws = wsum[t];
#pragma unroll
        for (int off = 1; off < 16; off <<= 1) {
            int u = __shfl_up(ws, off);
            if (t >= off) ws += u;
        }
        wsum[t] = ws;
    }
    __syncthreads();
    int off = (w > 0) ? wsum[w - 1] : 0;
    if (i < NN) row_start[i] = off + s - v;
    if (t == 1023) bsum[blockIdx.x] = off + s;
}

__global__ void k_scan2(int* __restrict__ bsum, int* __restrict__ row_start) {
    int t = threadIdx.x;
    int v = (t < NBLK) ? bsum[t] : 0;
    int s = v;
#pragma unroll
    for (int off = 1; off < 64; off <<= 1) {
        int u = __shfl_up(s, off);
        if (t >= off) s += u;
    }
    if (t < NBLK) bsum[t] = s - v;
    if (t == 0) row_start[NN] = EE;
}

__global__ void k_init2(const int* __restrict__ deg, const int* __restrict__ bsum,
                        int* __restrict__ row_start, int* __restrict__ cursor,
                        float* __restrict__ invd) {
    int i = blockIdx.x * 1024 + threadIdx.x;
    if (i < NN) {
        int r = row_start[i] + bsum[blockIdx.x];
        row_start[i] = r;
        cursor[i] = r;
        int d = deg[i];
        invd[i] = d > 0 ? 1.0f / (float)d : 0.0f;
    }
}

__global__ void k_scatter(const int* __restrict__ src, const int* __restrict__ tgt,
                          int* __restrict__ cursor, int* __restrict__ csr) {
    int e = blockIdx.x * 256 + threadIdx.x;
    if (e < EE) {
        int p = atomicAdd(&cursor[tgt[e]], 1);
        csr[p] = src[e];
    }
}

// ------- weight prep: fp32 W[i][k][n] -> transposed bf16 hi/lo Wt[i][n][k] -------
__global__ void k_wprep(const float* __restrict__ Wl, const float* __restrict__ Wr,
                        uint16_t* __restrict__ wtl_hi, uint16_t* __restrict__ wtl_lo,
                        uint16_t* __restrict__ wtr_hi, uint16_t* __restrict__ wtr_lo) {
    int d = blockIdx.x * 256 + threadIdx.x;
    int i = d >> 16, n = (d >> 8) & 255, k = d & 255;
    int s = (i << 16) | (k << 8) | n;
    float wl = Wl[s], wr = Wr[s];
    uint32_t ul = __float_as_uint(wl), ur = __float_as_uint(wr);
    wtl_hi[d] = (uint16_t)(ul >> 16);
    wtl_lo[d] = f2bf(wl - __uint_as_float(ul & 0xFFFF0000u));
    wtr_hi[d] = (uint16_t)(ur >> 16);
    wtr_lo[d] = f2bf(wr - __uint_as_float(ur & 0xFFFF0000u));
}

// ---- split x_init fp32 -> xs2 bf16 [NPAD][512]: cols 0-255 hi, 256-511 lo ----
__global__ void k_split0(const float* __restrict__ x, uint16_t* __restrict__ xs2) {
    int t = threadIdx.x;
    int row = blockIdx.x * 4 + (t >> 6);
    int col = (t & 63) * 4;
    uint32_t h01 = 0, h23 = 0, l01 = 0, l23 = 0;
    if (row < NN) {
        float4 v = *reinterpret_cast<const float4*>(x + (size_t)row * DD + col);
        uint32_t u0 = __float_as_uint(v.x), u1 = __float_as_uint(v.y);
        uint32_t u2 = __float_as_uint(v.z), u3 = __float_as_uint(v.w);
        h01 = (u0 >> 16) | (u1 & 0xFFFF0000u);
        h23 = (u2 >> 16) | (u3 & 0xFFFF0000u);
        l01 = (uint32_t)f2bf(v.x - __uint_as_float(u0 & 0xFFFF0000u))
            | ((uint32_t)f2bf(v.y - __uint_as_float(u1 & 0xFFFF0000u)) << 16);
        l23 = (uint32_t)f2bf(v.z - __uint_as_float(u2 & 0xFFFF0000u))
            | ((uint32_t)f2bf(v.w - __uint_as_float(u3 & 0xFFFF0000u)) << 16);
    }
    *reinterpret_cast<uint2*>(xs2 + (size_t)row * 512 + col) = make_uint2(h01, h23);
    *reinterpret_cast<uint2*>(xs2 + (size_t)row * 512 + 256 + col) = make_uint2(l01, l23);
}

// ---- dual GEMM, barrier-free K-loop: yl = x@Wl (bf16 out), z = x@Wr -> out slice ----
// Block: 256 rows x 32 cols, 4 waves (wave = 64 rows x 32 cols, acc 4rt x 2ct x 2out).
// B: all 4 mats (Wh_l,Wh_r,Wlo_l,Wlo_r for these 32 cols) = 64KB LDS, staged ONCE,
// bank-swizzled (slot ^ (n&7) -> 2-way = free). A: bf16 split pairs from xs2,
// register double-buffered (prefetch chunk c+1 during chunk c's MFMA). One barrier total.
__global__ __launch_bounds__(256, 2) void k_gemm4(
    const uint16_t* __restrict__ xs2,
    const uint16_t* __restrict__ whl, const uint16_t* __restrict__ whr,
    const uint16_t* __restrict__ wll, const uint16_t* __restrict__ wlr,
    uint16_t* __restrict__ yl, float* __restrict__ outz)
{
    extern __shared__ __align__(16) char smem[];   // 4 mats x 16KB = 64KB
    int t = threadIdx.x;
    int wave = t >> 6, lane = t & 63, quad = lane >> 4, l16 = lane & 15;
    int row0 = (blockIdx.x >> 3) * 256, col0 = (blockIdx.x & 7) * 32;

    // stage B once: LDS[m*16KB + i*4KB + t*16] = W[col0 + i*8 + (t>>5)][((t&31)^(t>>5))*8 ..]
    {
        const uint16_t* mp0 = whl + col0 * 256;
        const uint16_t* mp1 = whr + col0 * 256;
        const uint16_t* mp2 = wll + col0 * 256;
        const uint16_t* mp3 = wlr + col0 * 256;
        int nrow = t >> 5;
        int soff = ((t & 31) ^ nrow) * 8;
#pragma unroll
        for (int i = 0; i < 4; ++i) {
            int go = (i * 8 + nrow) * 256 + soff;
            char* d = smem + i * 4096 + t * 16;
            async_copy16(mp0 + go, d);
            async_copy16(mp1 + go, d + 16384);
            async_copy16(mp2 + go, d + 32768);
            async_copy16(mp3 + go, d + 49152);
        }
    }

    // A fragment pointers (per row-tile); frag = 16B at [row][c*32 + quad*8]
    const uint16_t* ap[4];
#pragma unroll
    for (int rt = 0; rt < 4; ++rt)
        ap[rt] = xs2 + (size_t)(row0 + wave * 64 + rt * 16 + l16) * 512 + quad * 8;

    floatx4 accy[4][2], accz[4][2];
#pragma unroll
    for (int rt = 0; rt < 4; ++rt)
#pragma unroll
        for (int ct = 0; ct < 2; ++ct) {
            accy[rt][ct] = (floatx4){0.f, 0.f, 0.f, 0.f};
            accz[rt][ct] = (floatx4){0.f, 0.f, 0.f, 0.f};
        }

    U8 abuf[2][4];
#pragma unroll
    for (int rt = 0; rt < 4; ++rt)
        abuf[0][rt].v = *reinterpret_cast<const shortx8*>(ap[rt]);

    __syncthreads();   // B (and A chunk 0) resident; no further barriers

    int bbase0 = l16 * 512;          // ct=0 B-row byte offset
    int bbase1 = (16 + l16) * 512;   // ct=1
    int bxor = l16 & 7;

#pragma unroll
    for (int c = 0; c < 16; ++c) {
        if (c < 15) {
#pragma unroll
            for (int rt = 0; rt < 4; ++rt)
                abuf[(c + 1) & 1][rt].v =
                    *reinterpret_cast<const shortx8*>(ap[rt] + (c + 1) * 32);
        }
        int kk = c & 7;
        int so = ((kk * 4 + quad) ^ bxor) * 16;
        shortx8 b00 = *reinterpret_cast<const shortx8*>(smem + bbase0 + so);           // Wh_l ct0
        shortx8 b10 = *reinterpret_cast<const shortx8*>(smem + bbase1 + so);           // Wh_l ct1
        shortx8 b01 = *reinterpret_cast<const shortx8*>(smem + 16384 + bbase0 + so);   // Wh_r ct0
        shortx8 b11 = *reinterpret_cast<const shortx8*>(smem + 16384 + bbase1 + so);   // Wh_r ct1
        shortx8 c00, c10, c01, c11;
        if (c < 8) {
            c00 = *reinterpret_cast<const shortx8*>(smem + 32768 + bbase0 + so);       // Wlo_l
            c10 = *reinterpret_cast<const shortx8*>(smem + 32768 + bbase1 + so);
            c01 = *reinterpret_cast<const shortx8*>(smem + 49152 + bbase0 + so);       // Wlo_r
            c11 = *reinterpret_cast<const shortx8*>(smem + 49152 + bbase1 + so);
        }
#pragma unroll
        for (int rt = 0; rt < 4; ++rt) {
            shortx8 a = abuf[c & 1][rt].v;
            accy[rt][0] = __builtin_amdgcn_mfma_f32_16x16x32_bf16(a, b00, accy[rt][0], 0, 0, 0);
            accy[rt][1] = __builtin_amdgcn_mfma_f32_16x16x32_bf16(a, b10, accy[rt][1], 0, 0, 0);
            accz[rt][0] = __builtin_amdgcn_mfma_f32_16x16x32_bf16(a, b01, accz[rt][0], 0, 0, 0);
            accz[rt][1] = __builtin_amdgcn_mfma_f32_16x16x32_bf16(a, b11, accz[rt][1], 0, 0, 0);
            if (c < 8) {   // xh pairs with Wlo too; xl (c>=8) pairs with Wh only
                accy[rt][0] = __builtin_amdgcn_mfma_f32_16x16x32_bf16(a, c00, accy[rt][0], 0, 0, 0);
                accy[rt][1] = __builtin_amdgcn_mfma_f32_16x16x32_bf16(a, c10, accy[rt][1], 0, 0, 0);
                accz[rt][0] = __builtin_amdgcn_mfma_f32_16x16x32_bf16(a, c01, accz[rt][0], 0, 0, 0);
                accz[rt][1] = __builtin_amdgcn_mfma_f32_16x16x32_bf16(a, c11, accz[rt][1], 0, 0, 0);
            }
        }
    }

    // epilogue: C/D layout col=l16, row=quad*4+r; bias/residual/relu deferred to k_finish
#pragma unroll
    for (int rt = 0; rt < 4; ++rt) {
#pragma unroll
        for (int ct = 0; ct < 2; ++ct) {
            int colg = col0 + ct * 16 + l16;
#pragma unroll
            for (int r = 0; r < 4; ++r) {
                int rowg = row0 + wave * 64 + rt * 16 + quad * 4 + r;
                if (rowg < NN) {
                    yl[(size_t)rowg * 256 + colg] = f2bf(accy[rt][ct][r]);
                    outz[(size_t)rowg * (LL * DD) + colg] = accz[rt][ct][r];
                }
            }
        }
    }
}

// ---- finish: out = maybe_relu(z + b + x + invd*sum yl[nbr]); also write next xs2 ----
__global__ __launch_bounds__(256) void k_finish(
    const int* __restrict__ rs, const int* __restrict__ csr,
    const float* __restrict__ invd, const uint16_t* __restrict__ yl,
    uint16_t* __restrict__ xs2, const float* __restrict__ bias,
    float* __restrict__ outz, int do_relu, int wsplit)
{
    int node = blockIdx.x * 4 + (threadIdx.x >> 6);
    int lane = threadIdx.x & 63;
    int col = lane * 4;
    int s = rs[node], e = rs[node + 1];
    float a0 = 0.f, a1 = 0.f, a2 = 0.f, a3 = 0.f;
    int p = s;
    for (; p + 4 <= e; p += 4) {
        int i0 = csr[p], i1 = csr[p + 1], i2 = csr[p + 2], i3 = csr[p + 3];
        uint2 v0 = *reinterpret_cast<const uint2*>(yl + (size_t)i0 * 256 + col);
        uint2 v1 = *reinterpret_cast<const uint2*>(yl + (size_t)i1 * 256 + col);
        uint2 v2 = *reinterpret_cast<const uint2*>(yl + (size_t)i2 * 256 + col);
        uint2 v3 = *reinterpret_cast<const uint2*>(yl + (size_t)i3 * 256 + col);
        a0 += (bf2f(v0.x) + bf2f(v1.x)) + (bf2f(v2.x) + bf2f(v3.x));
        a1 += (bf2f(v0.x >> 16) + bf2f(v1.x >> 16)) + (bf2f(v2.x >> 16) + bf2f(v3.x >> 16));
        a2 += (bf2f(v0.y) + bf2f(v1.y)) + (bf2f(v2.y) + bf2f(v3.y));
        a3 += (bf2f(v0.y >> 16) + bf2f(v1.y >> 16)) + (bf2f(v2.y >> 16) + bf2f(v3.y >> 16));
    }
    for (; p < e; ++p) {
        int i = csr[p];
        uint2 v = *reinterpret_cast<const uint2*>(yl + (size_t)i * 256 + col);
        a0 += bf2f(v.x); a1 += bf2f(v.x >> 16); a2 += bf2f(v.y); a3 += bf2f(v.y >> 16);
    }
    float w = invd[node];
    float* zp = outz + (size_t)node * (LL * DD) + col;
    float4 z = *reinterpret_cast<const float4*>(zp);
    float4 b = *reinterpret_cast<const float4*>(bias + col);
    uint2 xh = *reinterpret_cast<const uint2*>(xs2 + (size_t)node * 512 + col);
    uint2 xl = *reinterpret_cast<const uint2*>(xs2 + (size_t)node * 512 + 256 + col);
    float o0 = z.x + b.x + (bf2f(xh.x) + bf2f(xl.x)) + w * a0;
    float o1 = z.y + b.y + (bf2f(xh.x >> 16) + bf2f(xl.x >> 16)) + w * a1;
    float o2 = z.z + b.z + (bf2f(xh.y) + bf2f(xl.y)) + w * a2;
    float o3 = z.w + b.w + (bf2f(xh.y >> 16) + bf2f(xl.y >> 16)) + w * a3;
    if (do_relu) {
        o0 = fmaxf(o0, 0.f); o1 = fmaxf(o1, 0.f);
        o2 = fmaxf(o2, 0.f); o3 = fmaxf(o3, 0.f);
    }
    *reinterpret_cast<float4*>(zp) = make_float4(o0, o1, o2, o3);
    if (wsplit) {   // write next layer's split input
        uint32_t u0 = __float_as_uint(o0), u1 = __float_as_uint(o1);
        uint32_t u2 = __float_as_uint(o2), u3 = __float_as_uint(o3);
        uint32_t h01 = (u0 >> 16) | (u1 & 0xFFFF0000u);
        uint32_t h23 = (u2 >> 16) | (u3 & 0xFFFF0000u);
        uint32_t l01 = (uint32_t)f2bf(o0 - __uint_as_float(u0 & 0xFFFF0000u))
                     | ((uint32_t)f2bf(o1 - __uint_as_float(u1 & 0xFFFF0000u)) << 16);
        uint32_t l23 = (uint32_t)f2bf(o2 - __uint_as_float(u2 & 0xFFFF0000u))
                     | ((uint32_t)f2bf(o3 - __uint_as_float(u3 & 0xFFFF0000u)) << 16);
        *reinterpret_cast<uint2*>(xs2 + (size_t)node * 512 + col) = make_uint2(h01, h23);
        *reinterpret_cast<uint2*>(xs2 + (size_t)node * 512 + 256 + col) = make_uint2(l01, l23);
    }
}

extern "C" void kernel_launch(void* const* d_in, const int* in_sizes, int n_in,
                              void* d_out, int out_size, void* d_ws, size_t ws_size,
                              hipStream_t stream) {
    const int*   edge   = (const int*)d_in[0];     // [2][E]: row0=src, row1=tgt
    const float* x_init = (const float*)d_in[1];   // [N][D] fp32
    const float* W_l    = (const float*)d_in[2];   // [L][D][D] fp32
    const float* W_r    = (const float*)d_in[3];   // [L][D][D] fp32
    const float* bias   = (const float*)d_in[4];   // [L][D] fp32
    float*       out    = (float*)d_out;           // [N][L*D] fp32

    char* ws = (char*)d_ws;
    int*      degI      = (int*)(ws + 0x0000000);
    int*      row_start = (int*)(ws + 0x0040000);
    int*      cursor    = (int*)(ws + 0x0080000);
    float*    invd      = (float*)(ws + 0x00C0000);
    int*      bsum      = (int*)(ws + 0x0100000);
    int*      csr       = (int*)(ws + 0x0140000);        // 3.2 MB
    uint16_t* whl       = (uint16_t*)(ws + 0x0480000);   // 384 KB each (3 layers)
    uint16_t* whr       = (uint16_t*)(ws + 0x04E0000);
    uint16_t* wll       = (uint16_t*)(ws + 0x0540000);
    uint16_t* wlr       = (uint16_t*)(ws + 0x05A0000);
    uint16_t* yl        = (uint16_t*)(ws + 0x0600000);   // NPAD*256*2 = 25.7 MB
    uint16_t* xs2       = (uint16_t*)(ws + 0x1E80000);   // NPAD*512*2 = 51.4 MB (ends ~83 MB)

    hipMemsetAsync(degI, 0, NN * sizeof(int), stream);
    k_count<<<(EE + 255) / 256, 256, 0, stream>>>(edge + EE, degI);
    k_scan1<<<NBLK, 1024, 0, stream>>>(degI, row_start, bsum);
    k_scan2<<<1, 64, 0, stream>>>(bsum, row_start);
    k_init2<<<NBLK, 1024, 0, stream>>>(degI, bsum, row_start, cursor, invd);
    k_scatter<<<(EE + 255) / 256, 256, 0, stream>>>(edge, edge + EE, cursor, csr);
    k_wprep<<<(LL * DD * DD) / 256, 256, 0, stream>>>(W_l, W_r, whl, wll, whr, wlr);
    k_split0<<<NPAD / 4, 256, 0, stream>>>(x_init, xs2);

    for (int i = 0; i < LL; ++i) {
        size_t wo = (size_t)i * DD * DD;
        k_gemm4<<<(NPAD / 256) * 8, 256, 65536, stream>>>(
            xs2, whl + wo, whr + wo, wll + wo, wlr + wo,
            yl, out + (size_t)i * DD);
        k_finish<<<NN / 4, 256, 0, stream>>>(
            row_start, csr, invd, yl, xs2, bias + (size_t)i * DD,
            out + (size_t)i * DD, (i < LL - 1) ? 1 : 0, (i < LL - 1) ? 1 : 0);
    }
}